// Round 8
// baseline (300.139 us; speedup 1.0000x reference)
//
#include <hip/hip_runtime.h>
#include <hip/hip_bf16.h>

// Binarized-weight 3x3 conv as implicit GEMM:
//   out[n,o,h,w] = sum_{c,kh,kw} sign(W[o,c,kh,kw]) * x[n,c,h+kh-1,w+kw-1]
// GEMM: D[o][p] = sum_k Wmat[o][k] * B[k][p],  k = (kh*3+kw)*128 + c.
// R10 = R2 (best measured: gemm ~81us, VGPR 104, no spill) + ONE change:
// A fragments read directly from a fragment-native weight layout
// wm2[j][c8][o][8c] (L2-resident 576 KB; per-lane 16B load == R2's staged
// fragment, address algebra validated by passing R8/R9). This removes
// A-LDS, all A-staging glds, and 24 of R2's 36 barriers. No circular
// buffers, no hand vmcnt, no sched fences (R5-R9 post-mortems: every
// hand-scheduled variant spilled ~60 regs -> 104us; R2's compact
// structure + 2-blocks/CU TLP is the proven latency hider).
// Per (cc,kh): stageB (9 glds) -> __syncthreads (full drain) ->
// 3 kw x { direct-A loads, ds_read B, 32 MFMA } -> __syncthreads.
// No glds in flight when A register-loads wait (no R4 vmcnt trap).

typedef short bf16x8 __attribute__((ext_vector_type(8)));
typedef float f32x4 __attribute__((ext_vector_type(4)));

#define XT_ELEMS (32 * 66 * 66 * 128)
#define XT_BYTES (XT_ELEMS * 2)

__device__ __forceinline__ void glds16(const void* g, const void* l) {
    __builtin_amdgcn_global_load_lds(
        (const __attribute__((address_space(1))) void*)g,
        (__attribute__((address_space(3))) void*)l, 16, 0, 0);
}

// weight OIHW fp32 -> wm2[((j*16 + c8)*256 + o)*8 + e] = sign(w[o][c8*8+e][j])
// (fragment-native: lane fragment (o, c8) = 16 contiguous bytes)
__global__ void prep_w_kernel(const float* __restrict__ w,
                              __hip_bfloat16* __restrict__ wm) {
    int tid = blockIdx.x * 256 + threadIdx.x;   // 294912 total, exact grid
    int e = tid & 7;
    int o = (tid >> 3) & 255;
    int c8 = (tid >> 11) & 15;
    int j = tid >> 15;                          // 0..8
    float v = w[o * 1152 + (c8 * 8 + e) * 9 + j];
    float s = (v > 0.f) ? 1.f : ((v < 0.f) ? -1.f : 0.f);
    wm[tid] = __float2bfloat16(s);
}

// x NCHW fp32 -> x_t[n][h+1][w+1][c] bf16 (66x66 spatial, zero halo).
// Coalesced both ways via LDS bounce; halo zeroing folded in (no memset).
__global__ void transpose_x_kernel(const float* __restrict__ x,
                                   __hip_bfloat16* __restrict__ xt) {
    __shared__ short tl[64 * 130];   // stride 130: +65 banks/row -> 2-way max
    const int t = threadIdx.x;
    const int n = blockIdx.x >> 6;
    const int h = blockIdx.x & 63;
    const float* xp = x + (size_t)n * 524288 + h * 64;
    // phase 1: lanes span w -> 256 B contiguous per wave-load
    for (int i = t; i < 8192; i += 256) {
        int w = i & 63, c = i >> 6;
        tl[w * 130 + c] = (short)__bfloat16_as_ushort(__float2bfloat16(xp[c * 4096 + w]));
    }
    // halo zeroing (disjoint addresses; no barrier needed vs phase 2)
    uint* xtn = (uint*)(xt + (size_t)n * 66 * 66 * 128);
    {
        int row = h + 1;
        if (t < 64)       xtn[(row * 66 + 0) * 64 + t] = 0u;        // col 0
        else if (t < 128) xtn[(row * 66 + 65) * 64 + (t - 64)] = 0u; // col 65
    }
    if (h == 0)  for (int i = t; i < 66 * 64; i += 256) xtn[i] = 0u;                  // row 0
    if (h == 63) for (int i = t; i < 66 * 64; i += 256) xtn[65 * 66 * 64 + i] = 0u;   // row 65
    __syncthreads();
    // phase 2: lanes span c (uint = 2 shorts) -> 256 B contiguous stores
    uint* xo = (uint*)(xt + ((size_t)(n * 66 + h + 1) * 66 + 1) * 128);
    for (int i = t; i < 4096; i += 256) {
        int c2 = i & 63;
        int w = i >> 6;
        xo[w * 64 + c2] = *(const uint*)(tl + w * 130 + c2 * 2);
    }
}

// Block: 128 o x 256 px (4 out rows of one n). 4 waves, each 64o x 128px.
// LDS: Bw 4x66-cell window, 33 KB, single-buffered (restaged per (cc,kh),
// reused across kw). 16B segs XOR-swizzled by (cell&7) so ds_read_b128 is
// 2-way max (R2-measured 0 conflicts). A direct from global (no LDS).
__global__ __launch_bounds__(256, 2) void gemm_kernel(
    const __hip_bfloat16* __restrict__ xt,
    const __hip_bfloat16* __restrict__ wm,
    float* __restrict__ out) {
    __shared__ short Bw[264 * 64];    // 33792 B: 264 cells x 8 segs x 16 B

    const int t = threadIdx.x;
    const int lane = t & 63;
    const int wv = t >> 6;            // 0..3
    const int l15 = lane & 15;
    const int quad = lane >> 4;

    const int bid = blockIdx.x;                       // 0..511
    const int px_blk = (bid & 7) * 64 + (bid >> 3);   // XCD-chunked (512%8==0)
    const int o_blk = blockIdx.y;                     // 0..1
    const int n = px_blk >> 4;
    const int h0 = (px_blk & 15) * 4;

    const int wo = (wv & 1) * 64;     // wave origin in o
    const int wp = (wv >> 1) * 128;   // wave origin in px
    const int wpr = wp >> 6;          // wave px-row origin (0 or 2)

    const short* xtS = (const short*)xt;
    // lane A base: o = o_blk*128 + wo + l15 (+i*16), c8 = quad (+kf*4+ccA)
    const short* aL = (const short*)wm +
        (size_t)(o_blk * 128 + wo + l15) * 8 + quad * 2048;

    f32x4 acc[4][8] = {};   // [o frag][px frag]

    for (int cc = 0; cc < 128; cc += 64) {
        const int ccA = (cc >> 6) * 8 * 2048;   // c8 += 8 for cc64
        for (int kh = 0; kh < 3; ++kh) {
            // --- stage B window: rows (h0+kh .. h0+kh+3) x 66 cols x 64 c
            // 2112 segs = 33 full wave-issues; dest contiguous per issue.
            const short* xw = xtS + ((size_t)(n * 66 + h0 + kh) * 66) * 128;
#pragma unroll
            for (int i = 0; i < 9; ++i) {
                int bidx = i * 4 + wv;
                if (bidx < 33) {
                    int l = bidx * 64 + lane;
                    int cell = l >> 3;
                    int q = l & 7;
                    int s = q ^ (cell & 7);
                    glds16(xw + cell * 128 + cc + s * 8, Bw + bidx * 512);
                }
            }
            __syncthreads();   // drain glds; B window visible to all waves
#pragma unroll
            for (int kw = 0; kw < 3; ++kw) {
                const int j = kh * 3 + kw;
                const short* ap = aL + j * 32768 + ccA;
#pragma unroll
                for (int kf = 0; kf < 2; ++kf) {
                    bf16x8 a[4], b[8];
#pragma unroll
                    for (int i = 0; i < 4; ++i)
                        a[i] = *(const bf16x8*)(ap + kf * 8192 + i * 128);
#pragma unroll
                    for (int i = 0; i < 8; ++i) {
                        int cell = (wpr + (i >> 2)) * 66 + (i & 3) * 16 + l15 + kw;
                        int seg = (kf * 4 + quad) ^ (cell & 7);
                        b[i] = *(const bf16x8*)(Bw + cell * 64 + seg * 8);
                    }
#pragma unroll
                    for (int i = 0; i < 4; ++i)
#pragma unroll
                        for (int jj = 0; jj < 8; ++jj)
                            acc[i][jj] = __builtin_amdgcn_mfma_f32_16x16x32_bf16(
                                a[i], b[jj], acc[i][jj], 0, 0, 0);
                }
            }
            __syncthreads();   // all waves done reading Bw before restage
        }
    }

    // Epilogue: C/D layout col=lane&15 (px), row=quad*4+reg (o)
    const int Pbase = px_blk * 256 + wp;
#pragma unroll
    for (int i = 0; i < 4; ++i) {
#pragma unroll
        for (int jj = 0; jj < 8; ++jj) {
            const int P = Pbase + jj * 16 + l15;
            const int hw = P & 4095;
            float* op = out + (size_t)n * 1048576 + hw;
#pragma unroll
            for (int r = 0; r < 4; ++r) {
                const int o = o_blk * 128 + wo + i * 16 + quad * 4 + r;
                op[(size_t)o * 4096] = acc[i][jj][r];
            }
        }
    }
}

extern "C" void kernel_launch(void* const* d_in, const int* in_sizes, int n_in,
                              void* d_out, int out_size, void* d_ws, size_t ws_size,
                              hipStream_t stream) {
    const float* x = (const float*)d_in[0];
    const float* w = (const float*)d_in[1];
    float* out = (float*)d_out;
    __hip_bfloat16* xt = (__hip_bfloat16*)d_ws;
    __hip_bfloat16* wm = (__hip_bfloat16*)((char*)d_ws + XT_BYTES);

    prep_w_kernel<<<1152, 256, 0, stream>>>(w, wm);
    transpose_x_kernel<<<2048, 256, 0, stream>>>(x, xt);
    gemm_kernel<<<dim3(512, 2), 256, 0, stream>>>(xt, wm, out);
}